// Round 15
// baseline (312.671 us; speedup 1.0000x reference)
//
#include <hip/hip_runtime.h>
#include <stdint.h>

// GraphConv (LightGCN-style), exact JAX threefry (partitionable) dropout.
// Round 15: per-hop COMPACTED lists (round 7) + XCD-routed scatter (round 13)
// — the routing fixes the 8x cross-XCD write amplification that killed the
// compacted scatter in round 7. spmm walks exactly the kept edges (no keep
// branch, half the ed iterations). No warm pass (round 14: regression).
//
// d_out layout: [N_NODES][N_HOPS+1][D] f32. Slice 0 = concat(user,item),
// slice h+1 = hop h output. Node order user-then-item == output concat order.

static constexpr int kUsers = 50000;
static constexpr int kItems = 100000;
static constexpr int kNodes = kUsers + kItems;   // 150000
static constexpr int kNnz   = 1000000;
static constexpr int kD     = 64;
static constexpr int kHops  = 3;
static constexpr int kRowF  = (kHops + 1) * kD;  // 256 floats per node row

// per-hop counter stride; scan covers 3 hops x 150528 = 441 blocks x 1024
static constexpr int kCntN        = 147 * 1024;          // 150528 >= kNodes+1
static constexpr int kScanBlocks3 = 3 * 147;             // 441
static constexpr int kCntTotal    = kScanBlocks3 * 1024; // 451584
static constexpr int kEdCap       = 1600000;             // kept total ~1.5M (fixed, index-only PRNG)

// route_scatter geometry: 8 groups x chunks of 8192 edges
static constexpr int kEPB     = 8192;
static constexpr int kChunks  = (kNnz + kEPB - 1) / kEPB;  // 123
static constexpr int kRowsPerGrp = kNodes / 8;             // 18750

// ---- JAX threefry2x32 (20 rounds), bit-exact -------------------------------
__host__ __device__ inline void tf2x32(uint32_t k0, uint32_t k1,
                                       uint32_t x0, uint32_t x1,
                                       uint32_t &o0, uint32_t &o1) {
  uint32_t ks2 = k0 ^ k1 ^ 0x1BD11BDAu;
  x0 += k0; x1 += k1;
#define TF_R(r) { x0 += x1; x1 = (x1 << (r)) | (x1 >> (32 - (r))); x1 ^= x0; }
  TF_R(13) TF_R(15) TF_R(26) TF_R(6)   x0 += k1;  x1 += ks2 + 1u;
  TF_R(17) TF_R(29) TF_R(16) TF_R(24)  x0 += ks2; x1 += k0 + 2u;
  TF_R(13) TF_R(15) TF_R(26) TF_R(6)   x0 += k0;  x1 += k1 + 3u;
  TF_R(17) TF_R(29) TF_R(16) TF_R(24)  x0 += k1;  x1 += ks2 + 4u;
  TF_R(13) TF_R(15) TF_R(26) TF_R(6)   x0 += ks2; x1 += k0 + 5u;
#undef TF_R
  o0 = x0; o1 = x1;
}

// partitionable random_bits(32): XOR-fold, counter (hi,lo) = (0, i)
__device__ inline uint32_t jax_bits32(uint32_t k0, uint32_t k1, uint32_t i) {
  uint32_t b1, b2;
  tf2x32(k0, k1, 0u, i, b1, b2);
  return b1 ^ b2;
}

__device__ inline float bits_to_unit(uint32_t b) {
  return __uint_as_float((b >> 9) | 0x3f800000u) - 1.0f;
}

// ---- fast path kernels ------------------------------------------------------

// slice0 init + zero all 3 hop counter arrays (separate dispatch BEFORE the
// atomic histogram — round-8 lesson: never fuse zeroing with the atomics).
__global__ __launch_bounds__(256) void init_slice0(
    const float4* __restrict__ user, const float4* __restrict__ item,
    float4* __restrict__ out, int4* __restrict__ cnt4) {
  int i = blockIdx.x * 256 + threadIdx.x;          // grid covers kNodes*16
  if (i < kCntTotal / 4) cnt4[i] = make_int4(0, 0, 0, 0);
  if (i >= kNodes * 16) return;
  int node = i >> 4, q = i & 15;
  float4 v = (node < kUsers) ? user[node * 16 + q]
                             : item[(node - kUsers) * 16 + q];
  out[(size_t)node * (kRowF / 4) + q] = v;
}

// per-hop kept histogram + SEQUENTIAL record build:
// rec[e] = {col | keep0<<29 | keep1<<30 | keep2<<31, 2*val}
__global__ __launch_bounds__(256) void hist_rec(
    const int* __restrict__ rows, const int* __restrict__ cols,
    const float* __restrict__ vals, int* __restrict__ cnt,
    uint2* __restrict__ rec,
    uint32_t e00, uint32_t e01, uint32_t e10, uint32_t e11,
    uint32_t e20, uint32_t e21) {
  int e = blockIdx.x * 256 + threadIdx.x;
  if (e >= kNnz) return;
  int r = rows[e];
  float u0 = bits_to_unit(jax_bits32(e00, e01, (uint32_t)e));
  float u1 = bits_to_unit(jax_bits32(e10, e11, (uint32_t)e));
  float u2 = bits_to_unit(jax_bits32(e20, e21, (uint32_t)e));
  bool kp0 = (0.5f + u0 >= 1.0f);
  bool kp1 = (0.5f + u1 >= 1.0f);
  bool kp2 = (0.5f + u2 >= 1.0f);
  if (kp0) atomicAdd(&cnt[r], 1);
  if (kp1) atomicAdd(&cnt[kCntN + r], 1);
  if (kp2) atomicAdd(&cnt[2 * kCntN + r], 1);
  uint32_t packed = (uint32_t)cols[e]
                  | (kp0 ? (1u << 29) : 0u)
                  | (kp1 ? (1u << 30) : 0u)
                  | (kp2 ? (1u << 31) : 0u);
  rec[e] = make_uint2(packed, __float_as_uint(vals[e] * 2.0f));
}

// scan phase A: per-block totals (1024 elems/block, int4 loads)
__global__ __launch_bounds__(256) void scanA(
    const int* __restrict__ cnt, int* __restrict__ partials) {
  int t = threadIdx.x;
  int4 v = ((const int4*)(cnt + blockIdx.x * 1024))[t];
  int s = v.x + v.y + v.z + v.w;
  __shared__ int sh[256];
  sh[t] = s; __syncthreads();
  for (int off = 128; off > 0; off >>= 1) {
    if (t < off) sh[t] += sh[t + off];
    __syncthreads();
  }
  if (t == 0) partials[blockIdx.x] = sh[0];
}

// scan phase B: exclusive scan of 441 partials (single block, 512 threads)
__global__ __launch_bounds__(512) void scanB(int* __restrict__ partials) {
  int t = threadIdx.x;
  int v = (t < kScanBlocks3) ? partials[t] : 0;
  __shared__ int sh[512];
  sh[t] = v; __syncthreads();
  for (int off = 1; off < 512; off <<= 1) {
    int a = (t >= off) ? sh[t - off] : 0;
    __syncthreads();
    sh[t] += a;
    __syncthreads();
  }
  if (t < kScanBlocks3) partials[t] = sh[t] - v;   // exclusive
}

// scan phase C: in-place block-local exclusive scan + base (cnt -> cursors X)
__global__ __launch_bounds__(256) void scanC(
    int* __restrict__ cnt, const int* __restrict__ partials) {
  int t = threadIdx.x;
  int4 v = ((const int4*)(cnt + blockIdx.x * 1024))[t];
  int s = v.x + v.y + v.z + v.w;
  __shared__ int sh[256];
  sh[t] = s; __syncthreads();
  for (int off = 1; off < 256; off <<= 1) {
    int a = (t >= off) ? sh[t - off] : 0;
    __syncthreads();
    sh[t] += a;
    __syncthreads();
  }
  int base = partials[blockIdx.x] + sh[t] - s;     // exclusive for elem 4t
  int4 o;
  o.x = base; o.y = base + v.x; o.z = o.y + v.y; o.w = o.z + v.z;
  ((int4*)(cnt + blockIdx.x * 1024))[t] = o;
}

// XCD-routed compacted scatter: block group g = blockIdx&7 scans ALL rows;
// for rows in its 1/8 range, scatters the edge into each hop list whose keep
// bit is set. Every ed line (in every hop list) is written by one XCD.
// After this, X[h*kCntN + r] == end of segment (h,r).
__global__ __launch_bounds__(256) void route_scatter(
    const int* __restrict__ rows, const uint2* __restrict__ rec,
    int* __restrict__ X, uint2* __restrict__ ed) {
  const int grp   = blockIdx.x & 7;
  const int chunk = blockIdx.x >> 3;
  const int lo = grp * kRowsPerGrp;
  const int hi = lo + kRowsPerGrp;
  const int base4 = chunk * (kEPB / 4);
  const int t = threadIdx.x;
#pragma unroll
  for (int k = 0; k < kEPB / 4 / 256; ++k) {
    int idx4 = base4 + k * 256 + t;
    if (idx4 >= kNnz / 4) break;
    int4 r4 = ((const int4*)rows)[idx4];
    int e0 = idx4 * 4;
    int rr[4] = {r4.x, r4.y, r4.z, r4.w};
#pragma unroll
    for (int j = 0; j < 4; ++j) {
      int r = rr[j];
      if (r >= lo && r < hi) {
        uint2 m = rec[e0 + j];
        if (m.x & (1u << 29)) {
          int pos = atomicAdd(&X[r], 1);
          if (pos < kEdCap) ed[pos] = m;
        }
        if (m.x & (1u << 30)) {
          int pos = atomicAdd(&X[kCntN + r], 1);
          if (pos < kEdCap) ed[pos] = m;
        }
        if (m.x & (1u << 31)) {
          int pos = atomicAdd(&X[2 * kCntN + r], 1);
          if (pos < kEdCap) ed[pos] = m;
        }
      }
    }
  }
}

// pull SpMM over kept-only lists: one wave per TWO consecutive rows; 8 edge-
// groups x 8 lanes per row, 2x float4 per lane; no keep-bit branch; fused
// message dropout.
__global__ __launch_bounds__(256) void csr_spmm(
    const int* __restrict__ X, const uint2* __restrict__ ed,
    float* __restrict__ out, int hop, uint32_t km0, uint32_t km1) {
  int pair = blockIdx.x * 4 + (threadIdx.x >> 6);
  int rA = pair * 2;
  if (rA >= kNodes) return;
  int lane = threadIdx.x & 63;
  int g = lane >> 3, q = lane & 7;
  int idx0 = hop * kCntN + rA;
  int sA = (idx0 == 0) ? 0 : X[idx0 - 1];
  int tA = X[idx0];
  int tB = X[idx0 + 1];                            // sB == tA
  float uA = bits_to_unit(jax_bits32(km0, km1, (uint32_t)(rA * kD + lane)));
  float uB = bits_to_unit(jax_bits32(km0, km1, (uint32_t)((rA + 1) * kD + lane)));
  float mA = (uA < 0.9f) ? (1.0f / 0.9f) : 0.0f;
  float mB = (uB < 0.9f) ? (1.0f / 0.9f) : 0.0f;
  float4 a0 = make_float4(0.f, 0.f, 0.f, 0.f);
  float4 a1 = make_float4(0.f, 0.f, 0.f, 0.f);
  float4 b0 = make_float4(0.f, 0.f, 0.f, 0.f);
  float4 b1 = make_float4(0.f, 0.f, 0.f, 0.f);
  const float* src = out + (size_t)hop * kD;
  int iA = sA + g, iB = tA + g;
  while (iA < tA || iB < tB) {
    if (iA < tA) {
      uint2 m = ed[iA];
      float v = __uint_as_float(m.y);
      const float* p = src + (size_t)(m.x & 0x3FFFFu) * kRowF + (q << 3);
      float4 x0 = *(const float4*)p;
      float4 x1 = *(const float4*)(p + 4);
      a0.x += v * x0.x; a0.y += v * x0.y; a0.z += v * x0.z; a0.w += v * x0.w;
      a1.x += v * x1.x; a1.y += v * x1.y; a1.z += v * x1.z; a1.w += v * x1.w;
      iA += 8;
    }
    if (iB < tB) {
      uint2 m = ed[iB];
      float v = __uint_as_float(m.y);
      const float* p = src + (size_t)(m.x & 0x3FFFFu) * kRowF + (q << 3);
      float4 x0 = *(const float4*)p;
      float4 x1 = *(const float4*)(p + 4);
      b0.x += v * x0.x; b0.y += v * x0.y; b0.z += v * x0.z; b0.w += v * x0.w;
      b1.x += v * x1.x; b1.y += v * x1.y; b1.z += v * x1.z; b1.w += v * x1.w;
      iB += 8;
    }
  }
#pragma unroll
  for (int msk = 8; msk <= 32; msk <<= 1) {
    a0.x += __shfl_xor(a0.x, msk); a0.y += __shfl_xor(a0.y, msk);
    a0.z += __shfl_xor(a0.z, msk); a0.w += __shfl_xor(a0.w, msk);
    a1.x += __shfl_xor(a1.x, msk); a1.y += __shfl_xor(a1.y, msk);
    a1.z += __shfl_xor(a1.z, msk); a1.w += __shfl_xor(a1.w, msk);
    b0.x += __shfl_xor(b0.x, msk); b0.y += __shfl_xor(b0.y, msk);
    b0.z += __shfl_xor(b0.z, msk); b0.w += __shfl_xor(b0.w, msk);
    b1.x += __shfl_xor(b1.x, msk); b1.y += __shfl_xor(b1.y, msk);
    b1.z += __shfl_xor(b1.z, msk); b1.w += __shfl_xor(b1.w, msk);
  }
  float w[8];
#pragma unroll
  for (int j = 0; j < 8; ++j) {
    float wA = __shfl(mA, (q << 3) + j);
    float wB = __shfl(mB, (q << 3) + j);
    w[j] = (g == 0) ? wA : wB;
  }
  if (g < 2) {
    int r = rA + g;
    float4 r0, r1;
    if (g == 0) {
      r0 = make_float4(a0.x * w[0], a0.y * w[1], a0.z * w[2], a0.w * w[3]);
      r1 = make_float4(a1.x * w[4], a1.y * w[5], a1.z * w[6], a1.w * w[7]);
    } else {
      r0 = make_float4(b0.x * w[0], b0.y * w[1], b0.z * w[2], b0.w * w[3]);
      r1 = make_float4(b1.x * w[4], b1.y * w[5], b1.z * w[6], b1.w * w[7]);
    }
    float* dst = out + (size_t)r * kRowF + (hop + 1) * kD + (q << 3);
    *(float4*)dst = r0;
    *(float4*)(dst + 4) = r1;
  }
}

// ---- fallback (round-2, proven) kernels -------------------------------------
__global__ __launch_bounds__(256) void init_full(
    const float4* __restrict__ user, const float4* __restrict__ item,
    float4* __restrict__ out) {
  int i = blockIdx.x * 256 + threadIdx.x;
  if (i >= kNodes * 16) return;
  int node = i >> 4, q = i & 15;
  float4 v = (node < kUsers) ? user[node * 16 + q]
                             : item[(node - kUsers) * 16 + q];
  float4 z = make_float4(0.f, 0.f, 0.f, 0.f);
  float4* row = out + (size_t)node * (kRowF / 4);
  row[q] = v; row[16 + q] = z; row[32 + q] = z; row[48 + q] = z;
}

__global__ __launch_bounds__(256) void spmm_atomic(
    const int* __restrict__ rows, const int* __restrict__ cols,
    const float* __restrict__ vals, float* __restrict__ out, int hop,
    uint32_t k0, uint32_t k1) {
  int e = (int)((blockIdx.x * 256u + threadIdx.x) >> 6);
  if (e >= kNnz) return;
  int lane = threadIdx.x & 63;
  float u = bits_to_unit(jax_bits32(k0, k1, (uint32_t)e));
  if (!(0.5f + u >= 1.0f)) return;
  float v = vals[e] * 2.0f;
  int r = rows[e], c = cols[e];
  float msg = v * out[(size_t)c * kRowF + hop * kD + lane];
  atomicAdd(&out[(size_t)r * kRowF + (hop + 1) * kD + lane], msg);
}

__global__ __launch_bounds__(256) void mdrop_kernel(
    float* __restrict__ out, int hop, uint32_t k0, uint32_t k1) {
  const int total = kNodes * kD;
  int j = blockIdx.x * 256 + threadIdx.x;
  if (j >= total) return;
  float u = bits_to_unit(jax_bits32(k0, k1, (uint32_t)j));
  int node = j >> 6, d = j & 63;
  size_t idx = (size_t)node * kRowF + (hop + 1) * kD + d;
  float a = out[idx];
  out[idx] = (u < 0.9f) ? a / 0.9f : 0.0f;
}

// ---- launch -----------------------------------------------------------------
extern "C" void kernel_launch(void* const* d_in, const int* in_sizes, int n_in,
                              void* d_out, int out_size, void* d_ws, size_t ws_size,
                              hipStream_t stream) {
  const float* user = (const float*)d_in[0];
  const float* item = (const float*)d_in[1];
  const int*   rows = (const int*)d_in[2];
  const int*   cols = (const int*)d_in[3];
  const float* vals = (const float*)d_in[4];
  float* out = (float*)d_out;

  // host-side key schedule (partitionable split: subkey j = tf(key, 0, j))
  uint32_t k0 = 0u, k1 = 42u;                      // jax.random.key(42)
  uint32_t ke[kHops][2], km[kHops][2];
  for (int hop = 0; hop < kHops; ++hop) {
    uint32_t n0, n1;
    tf2x32(k0, k1, 0u, 0u, n0, n1);
    tf2x32(k0, k1, 0u, 1u, ke[hop][0], ke[hop][1]);
    tf2x32(k0, k1, 0u, 2u, km[hop][0], km[hop][1]);
    k0 = n0; k1 = n1;
  }

  // ws layout (4096-aligned): X (3x kCntN) | rec | ed | partials  (~23.5 MB)
  const size_t x_b   = (size_t)kCntTotal * 4;      // 1806336
  const size_t rec_b = ((size_t)kNnz * 8 + 4095) & ~(size_t)4095;   // 8003584
  const size_t ed_b  = (size_t)kEdCap * 8;         // 12800000
  const size_t par_b = 4096;
  const size_t need  = x_b + rec_b + ed_b + par_b;

  if (ws_size >= need) {
    char* ws = (char*)d_ws;
    int*   X        = (int*)ws;                    // cnt -> scan -> cursors
    uint2* rec      = (uint2*)(ws + x_b);
    uint2* ed       = (uint2*)(ws + x_b + rec_b);
    int*   partials = (int*)(ws + x_b + rec_b + ed_b);

    init_slice0<<<(kNodes * 16 + 255) / 256, 256, 0, stream>>>(
        (const float4*)user, (const float4*)item, (float4*)out, (int4*)X);
    hist_rec<<<(kNnz + 255) / 256, 256, 0, stream>>>(
        rows, cols, vals, X, rec,
        ke[0][0], ke[0][1], ke[1][0], ke[1][1], ke[2][0], ke[2][1]);
    scanA<<<kScanBlocks3, 256, 0, stream>>>(X, partials);
    scanB<<<1, 512, 0, stream>>>(partials);
    scanC<<<kScanBlocks3, 256, 0, stream>>>(X, partials);
    route_scatter<<<kChunks * 8, 256, 0, stream>>>(rows, rec, X, ed);

    const int nPairs = kNodes / 2;                 // 75000
    for (int hop = 0; hop < kHops; ++hop) {
      csr_spmm<<<(nPairs + 3) / 4, 256, 0, stream>>>(
          X, ed, out, hop, km[hop][0], km[hop][1]);
    }
  } else {
    // fallback: proven atomic path
    init_full<<<(kNodes * 16 + 255) / 256, 256, 0, stream>>>(
        (const float4*)user, (const float4*)item, (float4*)out);
    for (int hop = 0; hop < kHops; ++hop) {
      spmm_atomic<<<(kNnz * 64 + 255) / 256, 256, 0, stream>>>(
          rows, cols, vals, out, hop, ke[hop][0], ke[hop][1]);
      mdrop_kernel<<<(kNodes * kD + 255) / 256, 256, 0, stream>>>(
          out, hop, km[hop][0], km[hop][1]);
    }
  }
}

// Round 16
// 268.726 us; speedup vs baseline: 1.1635x; 1.1635x over previous
//
#include <hip/hip_runtime.h>
#include <stdint.h>

// GraphConv (LightGCN-style), exact JAX threefry (partitionable) dropout.
// Round 16: revert to round-13 winner (single packed list + XCD-routed
// scatter, keep-bit branch in spmm) + fold scanB into scanC (one fewer
// dispatch, validated round 14). Compaction (r7, r15) and warm (r14) are
// proven regressions; spmm gather is structural (~60us/hop, invariant to
// width/layout/MLP/cache across 7 probes).
//
// d_out layout: [N_NODES][N_HOPS+1][D] f32. Slice 0 = concat(user,item),
// slice h+1 = hop h output. Node order user-then-item == output concat order.

static constexpr int kUsers = 50000;
static constexpr int kItems = 100000;
static constexpr int kNodes = kUsers + kItems;   // 150000
static constexpr int kNnz   = 1000000;
static constexpr int kD     = 64;
static constexpr int kHops  = 3;
static constexpr int kRowF  = (kHops + 1) * kD;  // 256 floats per node row

// scan geometry: 147 blocks x 256 threads x 4 elems = 150528 >= kNodes+1
static constexpr int kScanBlocks = 147;
static constexpr int kCntN       = kScanBlocks * 1024;   // 150528

// route_scatter geometry: 8 groups x chunks of 8192 edges
static constexpr int kEPB     = 8192;
static constexpr int kChunks  = (kNnz + kEPB - 1) / kEPB;  // 123
static constexpr int kRowsPerGrp = kNodes / 8;             // 18750

// ---- JAX threefry2x32 (20 rounds), bit-exact -------------------------------
__host__ __device__ inline void tf2x32(uint32_t k0, uint32_t k1,
                                       uint32_t x0, uint32_t x1,
                                       uint32_t &o0, uint32_t &o1) {
  uint32_t ks2 = k0 ^ k1 ^ 0x1BD11BDAu;
  x0 += k0; x1 += k1;
#define TF_R(r) { x0 += x1; x1 = (x1 << (r)) | (x1 >> (32 - (r))); x1 ^= x0; }
  TF_R(13) TF_R(15) TF_R(26) TF_R(6)   x0 += k1;  x1 += ks2 + 1u;
  TF_R(17) TF_R(29) TF_R(16) TF_R(24)  x0 += ks2; x1 += k0 + 2u;
  TF_R(13) TF_R(15) TF_R(26) TF_R(6)   x0 += k0;  x1 += k1 + 3u;
  TF_R(17) TF_R(29) TF_R(16) TF_R(24)  x0 += k1;  x1 += ks2 + 4u;
  TF_R(13) TF_R(15) TF_R(26) TF_R(6)   x0 += ks2; x1 += k0 + 5u;
#undef TF_R
  o0 = x0; o1 = x1;
}

// partitionable random_bits(32): XOR-fold, counter (hi,lo) = (0, i)
__device__ inline uint32_t jax_bits32(uint32_t k0, uint32_t k1, uint32_t i) {
  uint32_t b1, b2;
  tf2x32(k0, k1, 0u, i, b1, b2);
  return b1 ^ b2;
}

__device__ inline float bits_to_unit(uint32_t b) {
  return __uint_as_float((b >> 9) | 0x3f800000u) - 1.0f;
}

// ---- fast path kernels ------------------------------------------------------

// slice0 init + cnt zeroing (separate dispatch BEFORE the atomic histogram)
__global__ __launch_bounds__(256) void init_slice0(
    const float4* __restrict__ user, const float4* __restrict__ item,
    float4* __restrict__ out, int4* __restrict__ cnt4) {
  int i = blockIdx.x * 256 + threadIdx.x;          // grid covers kNodes*16
  if (i < kCntN / 4) cnt4[i] = make_int4(0, 0, 0, 0);
  if (i >= kNodes * 16) return;
  int node = i >> 4, q = i & 15;
  float4 v = (node < kUsers) ? user[node * 16 + q]
                             : item[(node - kUsers) * 16 + q];
  out[(size_t)node * (kRowF / 4) + q] = v;
}

// histogram + SEQUENTIAL record build: rec[e] = {col|keep bits, 2*val}
__global__ __launch_bounds__(256) void hist_rec(
    const int* __restrict__ rows, const int* __restrict__ cols,
    const float* __restrict__ vals, int* __restrict__ cnt,
    uint2* __restrict__ rec,
    uint32_t e00, uint32_t e01, uint32_t e10, uint32_t e11,
    uint32_t e20, uint32_t e21) {
  int e = blockIdx.x * 256 + threadIdx.x;
  if (e >= kNnz) return;
  atomicAdd(&cnt[rows[e]], 1);
  float u0 = bits_to_unit(jax_bits32(e00, e01, (uint32_t)e));
  float u1 = bits_to_unit(jax_bits32(e10, e11, (uint32_t)e));
  float u2 = bits_to_unit(jax_bits32(e20, e21, (uint32_t)e));
  uint32_t packed = (uint32_t)cols[e]
                  | ((0.5f + u0 >= 1.0f) ? (1u << 29) : 0u)
                  | ((0.5f + u1 >= 1.0f) ? (1u << 30) : 0u)
                  | ((0.5f + u2 >= 1.0f) ? (1u << 31) : 0u);
  rec[e] = make_uint2(packed, __float_as_uint(vals[e] * 2.0f));
}

// scan phase A: per-block totals (1024 elems/block, int4 loads)
__global__ __launch_bounds__(256) void scanA(
    const int* __restrict__ cnt, int* __restrict__ partials) {
  int t = threadIdx.x;
  int4 v = ((const int4*)(cnt + blockIdx.x * 1024))[t];
  int s = v.x + v.y + v.z + v.w;
  __shared__ int sh[256];
  sh[t] = s; __syncthreads();
  for (int off = 128; off > 0; off >>= 1) {
    if (t < off) sh[t] += sh[t + off];
    __syncthreads();
  }
  if (t == 0) partials[blockIdx.x] = sh[0];
}

// scan phase C (scanB folded in): every block redundantly exclusive-scans
// the 147 partials in LDS, takes its own base, then does the local int4
// scan in place (cnt -> cursors X). Validated in round 14.
__global__ __launch_bounds__(256) void scanC(
    int* __restrict__ cnt, const int* __restrict__ partials) {
  int t = threadIdx.x;
  __shared__ int pp[256];
  __shared__ int blockBase;
  int pv = (t < kScanBlocks) ? partials[t] : 0;
  pp[t] = pv; __syncthreads();
  for (int off = 1; off < 256; off <<= 1) {
    int a = (t >= off) ? pp[t - off] : 0;
    __syncthreads();
    pp[t] += a;
    __syncthreads();
  }
  if (t == (int)blockIdx.x) blockBase = pp[t] - pv;   // exclusive prefix
  __syncthreads();

  int4 v = ((const int4*)(cnt + blockIdx.x * 1024))[t];
  int s = v.x + v.y + v.z + v.w;
  __shared__ int sh[256];
  sh[t] = s; __syncthreads();
  for (int off = 1; off < 256; off <<= 1) {
    int a = (t >= off) ? sh[t - off] : 0;
    __syncthreads();
    sh[t] += a;
    __syncthreads();
  }
  int base = blockBase + sh[t] - s;                // exclusive for elem 4t
  int4 o;
  o.x = base; o.y = base + v.x; o.z = o.y + v.y; o.w = o.z + v.z;
  ((int4*)(cnt + blockIdx.x * 1024))[t] = o;
}

// XCD-routed scatter (round-13 proven): block group g = blockIdx&7 scans all
// rows, scatters only rows in its 1/8 range -> each ed line written by one
// XCD (kills the 8x cross-XCD partial-line writeback amplification).
// After this, X[r] == row_end(r).
__global__ __launch_bounds__(256) void route_scatter(
    const int* __restrict__ rows, const uint2* __restrict__ rec,
    int* __restrict__ X, uint2* __restrict__ ed) {
  const int grp   = blockIdx.x & 7;
  const int chunk = blockIdx.x >> 3;
  const int lo = grp * kRowsPerGrp;
  const int hi = lo + kRowsPerGrp;
  const int base4 = chunk * (kEPB / 4);
  const int t = threadIdx.x;
#pragma unroll
  for (int k = 0; k < kEPB / 4 / 256; ++k) {
    int idx4 = base4 + k * 256 + t;
    if (idx4 >= kNnz / 4) break;
    int4 r4 = ((const int4*)rows)[idx4];
    int e0 = idx4 * 4;
    int rr[4] = {r4.x, r4.y, r4.z, r4.w};
#pragma unroll
    for (int j = 0; j < 4; ++j) {
      int r = rr[j];
      if (r >= lo && r < hi) {
        int pos = atomicAdd(&X[r], 1);
        ed[pos] = rec[e0 + j];
      }
    }
  }
}

// pull SpMM (round-6/13 proven): one wave per TWO consecutive rows; 8 edge-
// groups x 8 lanes per row, 2x float4 per lane; fused message dropout.
__global__ __launch_bounds__(256) void csr_spmm(
    const int* __restrict__ X, const uint2* __restrict__ ed,
    float* __restrict__ out, int hop, uint32_t km0, uint32_t km1) {
  int pair = blockIdx.x * 4 + (threadIdx.x >> 6);
  int rA = pair * 2;
  if (rA >= kNodes) return;
  int lane = threadIdx.x & 63;
  int g = lane >> 3, q = lane & 7;
  int sA = (rA == 0) ? 0 : X[rA - 1];
  int tA = X[rA];
  int tB = X[rA + 1];
  float uA = bits_to_unit(jax_bits32(km0, km1, (uint32_t)(rA * kD + lane)));
  float uB = bits_to_unit(jax_bits32(km0, km1, (uint32_t)((rA + 1) * kD + lane)));
  float mA = (uA < 0.9f) ? (1.0f / 0.9f) : 0.0f;
  float mB = (uB < 0.9f) ? (1.0f / 0.9f) : 0.0f;
  float4 a0 = make_float4(0.f, 0.f, 0.f, 0.f);
  float4 a1 = make_float4(0.f, 0.f, 0.f, 0.f);
  float4 b0 = make_float4(0.f, 0.f, 0.f, 0.f);
  float4 b1 = make_float4(0.f, 0.f, 0.f, 0.f);
  const float* src = out + (size_t)hop * kD;
  const uint32_t kbit = 1u << (29 + hop);
  int iA = sA + g, iB = tA + g;
  while (iA < tA || iB < tB) {
    if (iA < tA) {
      uint2 m = ed[iA];
      if (m.x & kbit) {
        float v = __uint_as_float(m.y);
        const float* p = src + (size_t)(m.x & 0x3FFFFu) * kRowF + (q << 3);
        float4 x0 = *(const float4*)p;
        float4 x1 = *(const float4*)(p + 4);
        a0.x += v * x0.x; a0.y += v * x0.y; a0.z += v * x0.z; a0.w += v * x0.w;
        a1.x += v * x1.x; a1.y += v * x1.y; a1.z += v * x1.z; a1.w += v * x1.w;
      }
      iA += 8;
    }
    if (iB < tB) {
      uint2 m = ed[iB];
      if (m.x & kbit) {
        float v = __uint_as_float(m.y);
        const float* p = src + (size_t)(m.x & 0x3FFFFu) * kRowF + (q << 3);
        float4 x0 = *(const float4*)p;
        float4 x1 = *(const float4*)(p + 4);
        b0.x += v * x0.x; b0.y += v * x0.y; b0.z += v * x0.z; b0.w += v * x0.w;
        b1.x += v * x1.x; b1.y += v * x1.y; b1.z += v * x1.z; b1.w += v * x1.w;
      }
      iB += 8;
    }
  }
#pragma unroll
  for (int msk = 8; msk <= 32; msk <<= 1) {
    a0.x += __shfl_xor(a0.x, msk); a0.y += __shfl_xor(a0.y, msk);
    a0.z += __shfl_xor(a0.z, msk); a0.w += __shfl_xor(a0.w, msk);
    a1.x += __shfl_xor(a1.x, msk); a1.y += __shfl_xor(a1.y, msk);
    a1.z += __shfl_xor(a1.z, msk); a1.w += __shfl_xor(a1.w, msk);
    b0.x += __shfl_xor(b0.x, msk); b0.y += __shfl_xor(b0.y, msk);
    b0.z += __shfl_xor(b0.z, msk); b0.w += __shfl_xor(b0.w, msk);
    b1.x += __shfl_xor(b1.x, msk); b1.y += __shfl_xor(b1.y, msk);
    b1.z += __shfl_xor(b1.z, msk); b1.w += __shfl_xor(b1.w, msk);
  }
  float w[8];
#pragma unroll
  for (int j = 0; j < 8; ++j) {
    float wA = __shfl(mA, (q << 3) + j);
    float wB = __shfl(mB, (q << 3) + j);
    w[j] = (g == 0) ? wA : wB;
  }
  if (g < 2) {
    int r = rA + g;
    float4 r0, r1;
    if (g == 0) {
      r0 = make_float4(a0.x * w[0], a0.y * w[1], a0.z * w[2], a0.w * w[3]);
      r1 = make_float4(a1.x * w[4], a1.y * w[5], a1.z * w[6], a1.w * w[7]);
    } else {
      r0 = make_float4(b0.x * w[0], b0.y * w[1], b0.z * w[2], b0.w * w[3]);
      r1 = make_float4(b1.x * w[4], b1.y * w[5], b1.z * w[6], b1.w * w[7]);
    }
    float* dst = out + (size_t)r * kRowF + (hop + 1) * kD + (q << 3);
    *(float4*)dst = r0;
    *(float4*)(dst + 4) = r1;
  }
}

// ---- fallback (round-2, proven) kernels -------------------------------------
__global__ __launch_bounds__(256) void init_full(
    const float4* __restrict__ user, const float4* __restrict__ item,
    float4* __restrict__ out) {
  int i = blockIdx.x * 256 + threadIdx.x;
  if (i >= kNodes * 16) return;
  int node = i >> 4, q = i & 15;
  float4 v = (node < kUsers) ? user[node * 16 + q]
                             : item[(node - kUsers) * 16 + q];
  float4 z = make_float4(0.f, 0.f, 0.f, 0.f);
  float4* row = out + (size_t)node * (kRowF / 4);
  row[q] = v; row[16 + q] = z; row[32 + q] = z; row[48 + q] = z;
}

__global__ __launch_bounds__(256) void spmm_atomic(
    const int* __restrict__ rows, const int* __restrict__ cols,
    const float* __restrict__ vals, float* __restrict__ out, int hop,
    uint32_t k0, uint32_t k1) {
  int e = (int)((blockIdx.x * 256u + threadIdx.x) >> 6);
  if (e >= kNnz) return;
  int lane = threadIdx.x & 63;
  float u = bits_to_unit(jax_bits32(k0, k1, (uint32_t)e));
  if (!(0.5f + u >= 1.0f)) return;
  float v = vals[e] * 2.0f;
  int r = rows[e], c = cols[e];
  float msg = v * out[(size_t)c * kRowF + hop * kD + lane];
  atomicAdd(&out[(size_t)r * kRowF + (hop + 1) * kD + lane], msg);
}

__global__ __launch_bounds__(256) void mdrop_kernel(
    float* __restrict__ out, int hop, uint32_t k0, uint32_t k1) {
  const int total = kNodes * kD;
  int j = blockIdx.x * 256 + threadIdx.x;
  if (j >= total) return;
  float u = bits_to_unit(jax_bits32(k0, k1, (uint32_t)j));
  int node = j >> 6, d = j & 63;
  size_t idx = (size_t)node * kRowF + (hop + 1) * kD + d;
  float a = out[idx];
  out[idx] = (u < 0.9f) ? a / 0.9f : 0.0f;
}

// ---- launch -----------------------------------------------------------------
extern "C" void kernel_launch(void* const* d_in, const int* in_sizes, int n_in,
                              void* d_out, int out_size, void* d_ws, size_t ws_size,
                              hipStream_t stream) {
  const float* user = (const float*)d_in[0];
  const float* item = (const float*)d_in[1];
  const int*   rows = (const int*)d_in[2];
  const int*   cols = (const int*)d_in[3];
  const float* vals = (const float*)d_in[4];
  float* out = (float*)d_out;

  // host-side key schedule (partitionable split: subkey j = tf(key, 0, j))
  uint32_t k0 = 0u, k1 = 42u;                      // jax.random.key(42)
  uint32_t ke[kHops][2], km[kHops][2];
  for (int hop = 0; hop < kHops; ++hop) {
    uint32_t n0, n1;
    tf2x32(k0, k1, 0u, 0u, n0, n1);
    tf2x32(k0, k1, 0u, 1u, ke[hop][0], ke[hop][1]);
    tf2x32(k0, k1, 0u, 2u, km[hop][0], km[hop][1]);
    k0 = n0; k1 = n1;
  }

  // ws layout (4096-aligned): X | rec | ed | partials  (~16.6 MB)
  const size_t x_b   = (size_t)kCntN * 4;          // 602112
  const size_t rec_b = ((size_t)kNnz * 8 + 4095) & ~(size_t)4095;  // 8003584
  const size_t ed_b  = rec_b;
  const size_t par_b = 4096;
  const size_t need  = x_b + rec_b + ed_b + par_b;

  if (ws_size >= need) {
    char* ws = (char*)d_ws;
    int*   X        = (int*)ws;                    // cnt -> scan -> cursors
    uint2* rec      = (uint2*)(ws + x_b);
    uint2* ed       = (uint2*)(ws + x_b + rec_b);
    int*   partials = (int*)(ws + x_b + rec_b + ed_b);

    init_slice0<<<(kNodes * 16 + 255) / 256, 256, 0, stream>>>(
        (const float4*)user, (const float4*)item, (float4*)out, (int4*)X);
    hist_rec<<<(kNnz + 255) / 256, 256, 0, stream>>>(
        rows, cols, vals, X, rec,
        ke[0][0], ke[0][1], ke[1][0], ke[1][1], ke[2][0], ke[2][1]);
    scanA<<<kScanBlocks, 256, 0, stream>>>(X, partials);
    scanC<<<kScanBlocks, 256, 0, stream>>>(X, partials);
    route_scatter<<<kChunks * 8, 256, 0, stream>>>(rows, rec, X, ed);

    const int nPairs = kNodes / 2;                 // 75000
    for (int hop = 0; hop < kHops; ++hop) {
      csr_spmm<<<(nPairs + 3) / 4, 256, 0, stream>>>(
          X, ed, out, hop, km[hop][0], km[hop][1]);
    }
  } else {
    // fallback: proven atomic path
    init_full<<<(kNodes * 16 + 255) / 256, 256, 0, stream>>>(
        (const float4*)user, (const float4*)item, (float4*)out);
    for (int hop = 0; hop < kHops; ++hop) {
      spmm_atomic<<<(kNnz * 64 + 255) / 256, 256, 0, stream>>>(
          rows, cols, vals, out, hop, ke[hop][0], ke[hop][1]);
      mdrop_kernel<<<(kNodes * kD + 255) / 256, 256, 0, stream>>>(
          out, hop, km[hop][0], km[hop][1]);
    }
  }
}